// Round 2
// baseline (241.184 us; speedup 1.0000x reference)
//
#include <hip/hip_runtime.h>

// Retention forward, chunkwise-linear, ONE fused kernel.
// Evidence (r1): both kernels < 41.5us (all top-5 rocprof dispatches are 41us
// harness fills) yet dur_us=105.6 -> >=22us is inter-dispatch/graph overhead.
// Fix: single dispatch. Blocks with c%4==0 run the A-role (group-of-4-chunk
// register scan -> L_c prefixes, T_g totals, verified in r0/r1) then publish a
// MAGIC flag (device-scope release). All blocks stage+intra first, then wave-0
// spin-waits (relaxed agent polls + s_sleep, bounded safety valve) on groups
// <= g, fences, reconstructs S, does cross + PV.
// Deadlock-free by capacity: LDS 27648B -> 5 blk/CU; __launch_bounds__(256,4)
// caps VGPR at 128 -> 4 blk/CU; grid 1024 == 256CU*4 -> ALL blocks resident.
// MAGIC flags need no init (poisoned ws != MAGIC); replay-without-repoison
// races are benign (producers rewrite byte-identical values).
// Design rules: grid.sync ~430us @1024 blocks (r4) — never. Per-block prefix
// re-scan = quadratic U traffic (+45us, r5) — never.

#define S_LEN 2048
#define DHEAD 64
#define CHUNK 64
#define NC    32
#define BH    32
#define LDK   72
#define MAGICF 0x9E3779B9u

typedef float  f32x4  __attribute__((ext_vector_type(4)));
typedef short  bf16x8 __attribute__((ext_vector_type(8)));
typedef unsigned short u16x8 __attribute__((ext_vector_type(8)));
typedef unsigned short u16x4 __attribute__((ext_vector_type(4)));

static __device__ __forceinline__ unsigned short f2bf(float f) {
    unsigned int u = __float_as_uint(f);
    u += 0x7FFFu + ((u >> 16) & 1u);
    return (unsigned short)(u >> 16);
}
static __device__ __forceinline__ float bf2f(unsigned short h) {
    return __uint_as_float((unsigned int)h << 16);
}

__global__ __launch_bounds__(256, 4)
void ret_fused(const float* __restrict__ qg, const float* __restrict__ kg,
               const float* __restrict__ vg, unsigned short* __restrict__ Lg,
               unsigned short* __restrict__ Tg, unsigned int* __restrict__ Fl,
               float* __restrict__ og) {
    const int c  = (int)blockIdx.x, bh = (int)blockIdx.y, h = bh & 15;
    const int tid = (int)threadIdx.x;
    const int wv = tid >> 6, ln = tid & 63, quad = ln >> 4, lnlo = ln & 15;
    const float sh = log2f(1.0f - exp2f(-5.0f - (float)h));   // < 0
    const int g = c >> 2;

    __shared__ __align__(16) unsigned short smem[3 * CHUNK * LDK];  // 27648 B
    unsigned short* const Ks  = smem;                   // A: weighted K^T | B: K [pos][d]
    unsigned short* const Vt  = smem + CHUNK * LDK;     // V^T [e][pos]
    unsigned short* const ShL = smem + 2 * CHUNK * LDK; // S^T [e][d]; reused as Ws

    const size_t bb = (size_t)bh * S_LEN * DHEAD;
    const size_t cb = bb + (size_t)c * CHUNK * DHEAD;

    if ((c & 3) == 0) {
        // ======== A-role: group-scan for group g (chunks 4g..4g+3) ========
        const float lamC = exp2f(sh * (float)CHUNK);
        float rk[2][8], rv[2][8];
        {
            const size_t cb0 = bb + (size_t)(4 * g) * CHUNK * DHEAD;
#pragma unroll
            for (int i2 = 0; i2 < 2; ++i2) {
                const int pos0 = wv * 8 + i2 * 32;
                const float* pK = kg + cb0 + (size_t)pos0 * DHEAD + ln;
                const float* pV = vg + cb0 + (size_t)pos0 * DHEAD + ln;
#pragma unroll
                for (int j = 0; j < 8; ++j) {
                    rk[i2][j] = pK[(size_t)j * DHEAD];
                    rv[i2][j] = pV[(size_t)j * DHEAD];
                }
            }
        }
        f32x4 Sreg[4];
#pragma unroll
        for (int nt = 0; nt < 4; ++nt) Sreg[nt] = (f32x4){0.f, 0.f, 0.f, 0.f};

        for (int i = 0; i < 4; ++i) {
            const int cc = 4 * g + i;
            if (i) {  // L_cc = state BEFORE chunk cc (group-local)
                unsigned short* lp = Lg + ((size_t)(bh * NC + cc) << 12);
#pragma unroll
                for (int nt = 0; nt < 4; ++nt) {
                    u16x4 w;
#pragma unroll
                    for (int r = 0; r < 4; ++r) w[r] = f2bf(Sreg[nt][r]);
                    *(u16x4*)&lp[(nt * 16 + lnlo) * 64 + wv * 16 + quad * 4] = w;
                }
            }
            if (g == 7 && i == 3) break;  // U_31 never consumed

#pragma unroll
            for (int i2 = 0; i2 < 2; ++i2) {
                const int pos0 = wv * 8 + i2 * 32;
                u16x8 tk, tv;
#pragma unroll
                for (int j = 0; j < 8; ++j) {
                    const float w = exp2f(sh * (float)(CHUNK - pos0 - j));
                    tk[j] = f2bf(rk[i2][j] * w);
                    tv[j] = f2bf(rv[i2][j]);
                }
                *(u16x8*)&Ks[ln * LDK + pos0] = tk;
                *(u16x8*)&Vt[ln * LDK + pos0] = tv;
            }
            __syncthreads();

            if (i < 3 && !(g == 7 && i == 2)) {  // prefetch next chunk
                const size_t cbn = bb + (size_t)(cc + 1) * CHUNK * DHEAD;
#pragma unroll
                for (int i2 = 0; i2 < 2; ++i2) {
                    const int pos0 = wv * 8 + i2 * 32;
                    const float* pK = kg + cbn + (size_t)pos0 * DHEAD + ln;
                    const float* pV = vg + cbn + (size_t)pos0 * DHEAD + ln;
#pragma unroll
                    for (int j = 0; j < 8; ++j) {
                        rk[i2][j] = pK[(size_t)j * DHEAD];
                        rv[i2][j] = pV[(size_t)j * DHEAD];
                    }
                }
            }

            bf16x8 aK[2];
#pragma unroll
            for (int ks = 0; ks < 2; ++ks)
                aK[ks] = *(const bf16x8*)&Ks[(wv * 16 + lnlo) * LDK + ks * 32 + quad * 8];
#pragma unroll
            for (int nt = 0; nt < 4; ++nt) {
                f32x4 a = (f32x4){0.f, 0.f, 0.f, 0.f};
#pragma unroll
                for (int ks = 0; ks < 2; ++ks) {
                    const bf16x8 bv = *(const bf16x8*)&Vt[(nt * 16 + lnlo) * LDK + ks * 32 + quad * 8];
                    a = __builtin_amdgcn_mfma_f32_16x16x32_bf16(aK[ks], bv, a, 0, 0, 0);
                }
#pragma unroll
                for (int r = 0; r < 4; ++r) Sreg[nt][r] = lamC * Sreg[nt][r] + a[r];
            }
            __syncthreads();
        }

        if (g < 7) {  // group total T_g
            unsigned short* tp = Tg + ((size_t)((bh << 3) + g) << 12);
#pragma unroll
            for (int nt = 0; nt < 4; ++nt) {
                u16x4 w;
#pragma unroll
                for (int r = 0; r < 4; ++r) w[r] = f2bf(Sreg[nt][r]);
                *(u16x4*)&tp[(nt * 16 + lnlo) * 64 + wv * 16 + quad * 4] = w;
            }
        }
        __syncthreads();  // all global writes drained (vmcnt(0) at barrier)
        if (tid == 0) {
            __threadfence();  // device-scope writeback before publish
            __hip_atomic_store(&Fl[(bh << 3) + g], MAGICF,
                               __ATOMIC_RELEASE, __HIP_MEMORY_SCOPE_AGENT);
        }
        // LDS free to reuse (barrier above); fall through to B-role.
    }

    // ======== B-role (all 1024 blocks): intra + cross for chunk c ========
    const float scale = 0.125f;
    const float* qp = qg + cb;
    const float* kp = kg + cb;
    const float* vp = vg + cb;
    float*       op = og + cb;

    // ---- stage K [pos][d] ----
    {
        const int kr = tid >> 2, kc0 = (tid & 3) * 16;
        const float* p = kp + (size_t)kr * DHEAD + kc0;
        const f32x4 x0 = *(const f32x4*)(p + 0);
        const f32x4 x1 = *(const f32x4*)(p + 4);
        const f32x4 x2 = *(const f32x4*)(p + 8);
        const f32x4 x3 = *(const f32x4*)(p + 12);
        u16x8 w0, w1;
        w0[0]=f2bf(x0[0]); w0[1]=f2bf(x0[1]); w0[2]=f2bf(x0[2]); w0[3]=f2bf(x0[3]);
        w0[4]=f2bf(x1[0]); w0[5]=f2bf(x1[1]); w0[6]=f2bf(x1[2]); w0[7]=f2bf(x1[3]);
        w1[0]=f2bf(x2[0]); w1[1]=f2bf(x2[1]); w1[2]=f2bf(x2[2]); w1[3]=f2bf(x2[3]);
        w1[4]=f2bf(x3[0]); w1[5]=f2bf(x3[1]); w1[6]=f2bf(x3[2]); w1[7]=f2bf(x3[3]);
        *(u16x8*)&Ks[kr * LDK + kc0]     = w0;
        *(u16x8*)&Ks[kr * LDK + kc0 + 8] = w1;
    }
    // ---- stage V^T [e][pos] ----
#pragma unroll
    for (int i = 0; i < 2; ++i) {
        const int pos0 = wv * 8 + i * 32;
        const float* p = vp + (size_t)pos0 * DHEAD + ln;
        u16x8 t;
#pragma unroll
        for (int j = 0; j < 8; ++j) t[j] = f2bf(p[(size_t)j * DHEAD]);
        *(u16x8*)&Vt[ln * LDK + pos0] = t;
    }
    // ---- Q A-fragments ----
    bf16x8 aQ[2];
    {
        const float* qrow = qp + (size_t)(wv * 16 + lnlo) * DHEAD;
#pragma unroll
        for (int ks = 0; ks < 2; ++ks) {
            const float* p = qrow + ks * 32 + quad * 8;
            bf16x8 a;
#pragma unroll
            for (int j = 0; j < 8; ++j) a[j] = (short)f2bf(p[j]);
            aQ[ks] = a;
        }
    }
    float rf[4];
#pragma unroll
    for (int r = 0; r < 4; ++r) rf[r] = exp2f((float)(wv * 16 + quad * 4 + r) * sh);

    __syncthreads();

    // ---- intra scores (no producer dependency) ----
    f32x4 acc[4];
#pragma unroll
    for (int nt = 0; nt < 4; ++nt) {
        f32x4 a = (f32x4){0.f, 0.f, 0.f, 0.f};
#pragma unroll
        for (int ks = 0; ks < 2; ++ks) {
            const bf16x8 bk = *(const bf16x8*)&Ks[(nt * 16 + lnlo) * LDK + ks * 32 + quad * 8];
            a = __builtin_amdgcn_mfma_f32_16x16x32_bf16(aQ[ks], bk, a, 0, 0, 0);
        }
        acc[nt] = a;
    }

    // ---- wait for producer groups <= g (wave 0 polls; others park at barrier) ----
    {
        const int glast = (c & 3) ? g : g - 1;
        if (wv == 0) {
            for (int gp = 0; gp <= glast; ++gp) {
                int it = 0;
                while (__hip_atomic_load(&Fl[(bh << 3) + gp], __ATOMIC_RELAXED,
                                         __HIP_MEMORY_SCOPE_AGENT) != MAGICF) {
                    __builtin_amdgcn_s_sleep(8);
                    if (++it > (1 << 22)) break;  // safety valve: fail visibly, never hang
                }
            }
            if (glast >= 0) __threadfence();  // invalidate caches before L/T reads
        }
        __syncthreads();
    }

    // ---- S^T = L_c + sum_{g'<g} lamC^(c-4g'-4) T_g' ----
    {
        const int r = tid >> 2, ccol = (tid & 3) * 16;
        float accS[16];
        if (c & 3) {
            const unsigned short* lp = Lg + ((size_t)(bh * NC + c) << 12) + (size_t)tid * 16;
            const u16x8 a0 = *(const u16x8*)lp;
            const u16x8 a1 = *(const u16x8*)(lp + 8);
#pragma unroll
            for (int j = 0; j < 8; ++j) { accS[j] = bf2f(a0[j]); accS[8 + j] = bf2f(a1[j]); }
        } else {
#pragma unroll
            for (int j = 0; j < 16; ++j) accS[j] = 0.f;
        }
        for (int gp = 0; gp < g; ++gp) {   // block-uniform trip count
            const float w = exp2f(sh * (float)(CHUNK * (c - 4 * gp - 4)));
            const unsigned short* tp = Tg + ((size_t)((bh << 3) + gp) << 12) + (size_t)tid * 16;
            const u16x8 t0 = *(const u16x8*)tp;
            const u16x8 t1 = *(const u16x8*)(tp + 8);
#pragma unroll
            for (int j = 0; j < 8; ++j) { accS[j] += w * bf2f(t0[j]); accS[8 + j] += w * bf2f(t1[j]); }
        }
        u16x8 w0, w1;
#pragma unroll
        for (int j = 0; j < 8; ++j) { w0[j] = f2bf(accS[j]); w1[j] = f2bf(accS[8 + j]); }
        *(u16x8*)&ShL[r * LDK + ccol]     = w0;
        *(u16x8*)&ShL[r * LDK + ccol + 8] = w1;
    }
    __syncthreads();

    // ---- cross: o = Q.S ----
    f32x4 o[4];
#pragma unroll
    for (int nt = 0; nt < 4; ++nt) {
        f32x4 a = (f32x4){0.f, 0.f, 0.f, 0.f};
#pragma unroll
        for (int ks = 0; ks < 2; ++ks) {
            const bf16x8 bs = *(const bf16x8*)&ShL[(nt * 16 + lnlo) * LDK + ks * 32 + quad * 8];
            a = __builtin_amdgcn_mfma_f32_16x16x32_bf16(aQ[ks], bs, a, 0, 0, 0);
        }
        o[nt] = a;
    }
#pragma unroll
    for (int nt = 0; nt < 4; ++nt)
#pragma unroll
        for (int r = 0; r < 4; ++r) o[nt][r] *= rf[r] * scale;

    __syncthreads();   // all waves done reading ShL before it becomes Ws

    // ---- decay*scale*causal; C-layout -> A-layout via LDS (same-wave rows) ----
#pragma unroll
    for (int nt = 0; nt < 4; ++nt) {
        const int jn = nt * 16 + lnlo;
        const float cf = scale * exp2f(-(float)jn * sh);
#pragma unroll
        for (int r = 0; r < 4; ++r) {
            const int ri = wv * 16 + quad * 4 + r;
            float wgt = acc[nt][r] * rf[r] * cf;
            if (ri < jn) wgt = 0.0f;
            ShL[ri * LDK + jn] = f2bf(wgt);
        }
    }
    const bf16x8 aW0 = *(const bf16x8*)&ShL[(wv * 16 + lnlo) * LDK + quad * 8];
    const bf16x8 aW1 = *(const bf16x8*)&ShL[(wv * 16 + lnlo) * LDK + 32 + quad * 8];

    // ---- O += P V ----
#pragma unroll
    for (int nt = 0; nt < 4; ++nt) {
        const bf16x8 bv0 = *(const bf16x8*)&Vt[(nt * 16 + lnlo) * LDK + quad * 8];
        const bf16x8 bv1 = *(const bf16x8*)&Vt[(nt * 16 + lnlo) * LDK + 32 + quad * 8];
        o[nt] = __builtin_amdgcn_mfma_f32_16x16x32_bf16(aW0, bv0, o[nt], 0, 0, 0);
        o[nt] = __builtin_amdgcn_mfma_f32_16x16x32_bf16(aW1, bv1, o[nt], 0, 0, 0);
    }

    // ---- epilogue: bounce through LDS -> coalesced dwordx4 stores ----
    __syncthreads();   // all waves done with Ks/Vt/ShL before overlay
    float* const Of = (float*)smem;   // 64 x 68 fp32 = 17408 B (< Ks+Vt = 18432 B)
#pragma unroll
    for (int nt = 0; nt < 4; ++nt)
#pragma unroll
        for (int r = 0; r < 4; ++r)
            Of[(wv * 16 + quad * 4 + r) * 68 + nt * 16 + lnlo] = o[nt][r];
    // rows [wv*16, wv*16+16) written and read by the same wave -> no barrier
    {
        const int row = tid >> 2, col0 = (tid & 3) * 16;
        const float* src = &Of[row * 68 + col0];
        float* dst = op + (size_t)row * DHEAD + col0;
        *(f32x4*)(dst + 0)  = *(const f32x4*)(src + 0);
        *(f32x4*)(dst + 4)  = *(const f32x4*)(src + 4);
        *(f32x4*)(dst + 8)  = *(const f32x4*)(src + 8);
        *(f32x4*)(dst + 12) = *(const f32x4*)(src + 12);
    }
}

extern "C" void kernel_launch(void* const* d_in, const int* in_sizes, int n_in,
                              void* d_out, int out_size, void* d_ws, size_t ws_size,
                              hipStream_t stream) {
    (void)in_sizes; (void)n_in; (void)out_size; (void)ws_size;
    const float* q = (const float*)d_in[0];
    const float* k = (const float*)d_in[1];
    const float* v = (const float*)d_in[2];
    float* o  = (float*)d_out;
    unsigned short* Lg = (unsigned short*)d_ws;                          // 8 MB bf16 local prefixes
    unsigned short* Tg = (unsigned short*)((char*)d_ws + (16u << 20));   // 2 MB bf16 group totals
    unsigned int*   Fl = (unsigned int*)((char*)d_ws + (20u << 20));     // 256 x u32 flags (MAGIC-valued, no init needed)

    dim3 blk(256, 1, 1);
    ret_fused<<<dim3(NC, BH, 1), blk, 0, stream>>>(q, k, v, Lg, Tg, Fl, o);
}

// Round 3
// 111.166 us; speedup vs baseline: 2.1696x; 2.1696x over previous
//
#include <hip/hip_runtime.h>

// Retention forward, chunkwise-linear, 4 wide-shallow stream-ordered kernels.
//   pA : per-chunk KV summaries U_c (MFMA, 992 blocks)          -> bf16 U
//   pB1: group-of-4 local prefixes L_c + totals T_g (512 blocks, depth-4 reg scan)
//   pB2: per-bh scan of T -> group-start states G_g (64 blocks, depth-7, loads upfront)
//   p3 : intra + cross with 2-term S build: S_c = L_c + lam^(c&3 chunks) * G_g
// Measured design rules:
//   - grid.sync ~430us @1024 blocks (r4) — never.
//   - per-block prefix re-scan = quadratic U traffic (+45us, r5) — never.
//   - cross-block flag/spin sync: 3x regression, MfmaUtil 0.4% (r2) — never.
//   - timed region = fixed ~41.5us harness fill + kernels; dispatch overhead ~0
//     (r0 3-dispatch == r1 2-dispatch). Extra shallow dispatches are free.
//   - bf16 intermediates fine: threshold 4.46, measured absmax 1.0.

#define S_LEN 2048
#define DHEAD 64
#define CHUNK 64
#define NC    32
#define BH    32
#define LDK   72

typedef float  f32x4  __attribute__((ext_vector_type(4)));
typedef short  bf16x8 __attribute__((ext_vector_type(8)));
typedef unsigned short u16x8 __attribute__((ext_vector_type(8)));
typedef unsigned short u16x4 __attribute__((ext_vector_type(4)));

static __device__ __forceinline__ unsigned short f2bf(float f) {
    unsigned int u = __float_as_uint(f);
    u += 0x7FFFu + ((u >> 16) & 1u);
    return (unsigned short)(u >> 16);
}
static __device__ __forceinline__ float bf2f(unsigned short h) {
    return __uint_as_float((unsigned int)h << 16);
}

// ---------------- pA: per-chunk KV summaries (U^T [e][d] bf16) ----------------
// (r0's verified p1, unchanged)
__global__ __launch_bounds__(256)
void ret_pA(const float* __restrict__ kg, const float* __restrict__ vg,
            unsigned short* __restrict__ Ug) {
    const int c  = (int)blockIdx.x, bh = (int)blockIdx.y, h = bh & 15;
    const int tid = (int)threadIdx.x;
    const int wv = tid >> 6, ln = tid & 63, quad = ln >> 4, lnlo = ln & 15;
    const float sh = log2f(1.0f - exp2f(-5.0f - (float)h));   // < 0

    __shared__ __align__(16) unsigned short Kt[CHUNK * LDK];  // lam-weighted K^T [d][j]
    __shared__ __align__(16) unsigned short Vt[CHUNK * LDK];  // V^T [e][j]

    const size_t cb = (size_t)bh * S_LEN * DHEAD + (size_t)c * CHUNK * DHEAD;
    const float* kp = kg + cb;
    const float* vp = vg + cb;

#pragma unroll
    for (int i = 0; i < 2; ++i) {
        const int pos0 = wv * 8 + i * 32;
        const float* pK = kp + (size_t)pos0 * DHEAD + ln;
        const float* pV = vp + (size_t)pos0 * DHEAD + ln;
        u16x8 tk, tv;
#pragma unroll
        for (int j = 0; j < 8; ++j) {
            const float w = exp2f(sh * (float)(CHUNK - pos0 - j));  // lam^(C - j_local)
            tk[j] = f2bf(pK[(size_t)j * DHEAD] * w);
            tv[j] = f2bf(pV[(size_t)j * DHEAD]);
        }
        *(u16x8*)&Kt[ln * LDK + pos0] = tk;
        *(u16x8*)&Vt[ln * LDK + pos0] = tv;
    }
    __syncthreads();

    bf16x8 aK[2];
#pragma unroll
    for (int ks = 0; ks < 2; ++ks)
        aK[ks] = *(const bf16x8*)&Kt[(wv * 16 + lnlo) * LDK + ks * 32 + quad * 8];

    unsigned short* up = Ug + ((size_t)(bh * NC + c) << 12);
#pragma unroll
    for (int nt = 0; nt < 4; ++nt) {
        f32x4 acc = (f32x4){0.f, 0.f, 0.f, 0.f};
#pragma unroll
        for (int ks = 0; ks < 2; ++ks) {
            const bf16x8 bv = *(const bf16x8*)&Vt[(nt * 16 + lnlo) * LDK + ks * 32 + quad * 8];
            acc = __builtin_amdgcn_mfma_f32_16x16x32_bf16(aK[ks], bv, acc, 0, 0, 0);
        }
        u16x4 w;
#pragma unroll
        for (int r = 0; r < 4; ++r) w[r] = f2bf(acc[r]);
        *(u16x4*)&up[(nt * 16 + lnlo) * 64 + wv * 16 + quad * 4] = w;
    }
}

// ---------------- pB1: L_c (group-local prefixes) + T_g (group totals) ----------------
// grid (16, 32): blockIdx.x = g*2 + half. Each thread scans 8 elems over 4 chunks.
__global__ __launch_bounds__(256)
void ret_pB1(const unsigned short* __restrict__ Ug, unsigned short* __restrict__ Lg,
             unsigned short* __restrict__ Tg) {
    const int gx = (int)blockIdx.x, bh = (int)blockIdx.y, h = bh & 15;
    const int g = gx >> 1, half = gx & 1;
    const int base = half * 2048 + (int)threadIdx.x * 8;
    const float sh   = log2f(1.0f - exp2f(-5.0f - (float)h));
    const float lamC = exp2f(sh * (float)CHUNK);

    const unsigned short* up = Ug + ((size_t)(bh * NC + 4 * g) << 12) + base;
    unsigned short*       lp = Lg + ((size_t)(bh * NC + 4 * g) << 12) + base;

    float t[8];
#pragma unroll
    for (int i = 0; i < 8; ++i) t[i] = 0.f;

#pragma unroll
    for (int j = 0; j < 4; ++j) {
        if (j) {  // L_{4g+j} = prefix state before chunk 4g+j
            u16x8 w;
#pragma unroll
            for (int i = 0; i < 8; ++i) w[i] = f2bf(t[i]);
            *(u16x8*)(lp + ((size_t)j << 12)) = w;
        }
        if (g == 7 && j == 3) break;  // U_31 never produced/needed
        const u16x8 a = *(const u16x8*)(up + ((size_t)j << 12));
#pragma unroll
        for (int i = 0; i < 8; ++i) t[i] = lamC * t[i] + bf2f(a[i]);
    }
    if (g < 7) {
        u16x8 w;
#pragma unroll
        for (int i = 0; i < 8; ++i) w[i] = f2bf(t[i]);
        *(u16x8*)(Tg + ((size_t)((bh << 3) + g) << 12) + base) = w;
    }
}

// ---------------- pB2: scan T -> group-start states G_g (g=1..7) ----------------
// grid (2, 32). All 7 T loads issued upfront; depth ~1 load latency + 7 reg FMAs.
__global__ __launch_bounds__(256)
void ret_pB2(const unsigned short* __restrict__ Tg, unsigned short* __restrict__ Gg) {
    const int half = (int)blockIdx.x, bh = (int)blockIdx.y, h = bh & 15;
    const int base = half * 2048 + (int)threadIdx.x * 8;
    const float sh   = log2f(1.0f - exp2f(-5.0f - (float)h));
    const float lam4 = exp2f(sh * (float)(4 * CHUNK));

    u16x8 tt[7];
#pragma unroll
    for (int g = 0; g < 7; ++g)
        tt[g] = *(const u16x8*)(Tg + ((size_t)((bh << 3) + g) << 12) + base);

    float G[8];
#pragma unroll
    for (int i = 0; i < 8; ++i) G[i] = 0.f;
#pragma unroll
    for (int g = 0; g < 7; ++g) {   // G_{g+1} = lam4 * G_g + T_g
        u16x8 w;
#pragma unroll
        for (int i = 0; i < 8; ++i) { G[i] = lam4 * G[i] + bf2f(tt[g][i]); w[i] = f2bf(G[i]); }
        *(u16x8*)(Gg + ((size_t)((bh << 3) + g + 1) << 12) + base) = w;
    }
}

// ---------------- p3: intra + cross (2-term S build: L_c + lam^(c&3)*G_g) ----------------
__global__ __launch_bounds__(256)
void ret_p3(const float* __restrict__ qg, const float* __restrict__ kg,
            const float* __restrict__ vg, const unsigned short* __restrict__ Lg,
            const unsigned short* __restrict__ Gg, float* __restrict__ og) {
    const int c  = (int)blockIdx.x, bh = (int)blockIdx.y, h = bh & 15;
    const int tid = (int)threadIdx.x;
    const int wv = tid >> 6, ln = tid & 63, quad = ln >> 4, lnlo = ln & 15;
    const float sh    = log2f(1.0f - exp2f(-5.0f - (float)h));
    const float scale = 0.125f;
    const int g = c >> 2;

    __shared__ __align__(16) unsigned short smem[3 * CHUNK * LDK];
    unsigned short* const Ks  = smem;                   // K [pos][d]
    unsigned short* const Vt  = smem + CHUNK * LDK;     // V^T [e][pos]
    unsigned short* const ShL = smem + 2 * CHUNK * LDK; // S^T [e][d]; reused as Ws

    const size_t cb = (size_t)bh * S_LEN * DHEAD + (size_t)c * CHUNK * DHEAD;
    const float* qp = qg + cb;
    const float* kp = kg + cb;
    const float* vp = vg + cb;
    float*       op = og + cb;

    // ---- stage K [pos][d] ----
    {
        const int kr = tid >> 2, kc0 = (tid & 3) * 16;
        const float* p = kp + (size_t)kr * DHEAD + kc0;
        const f32x4 x0 = *(const f32x4*)(p + 0);
        const f32x4 x1 = *(const f32x4*)(p + 4);
        const f32x4 x2 = *(const f32x4*)(p + 8);
        const f32x4 x3 = *(const f32x4*)(p + 12);
        u16x8 w0, w1;
        w0[0]=f2bf(x0[0]); w0[1]=f2bf(x0[1]); w0[2]=f2bf(x0[2]); w0[3]=f2bf(x0[3]);
        w0[4]=f2bf(x1[0]); w0[5]=f2bf(x1[1]); w0[6]=f2bf(x1[2]); w0[7]=f2bf(x1[3]);
        w1[0]=f2bf(x2[0]); w1[1]=f2bf(x2[1]); w1[2]=f2bf(x2[2]); w1[3]=f2bf(x2[3]);
        w1[4]=f2bf(x3[0]); w1[5]=f2bf(x3[1]); w1[6]=f2bf(x3[2]); w1[7]=f2bf(x3[3]);
        *(u16x8*)&Ks[kr * LDK + kc0]     = w0;
        *(u16x8*)&Ks[kr * LDK + kc0 + 8] = w1;
    }
    // ---- stage V^T [e][pos] ----
#pragma unroll
    for (int i = 0; i < 2; ++i) {
        const int pos0 = wv * 8 + i * 32;
        const float* p = vp + (size_t)pos0 * DHEAD + ln;
        u16x8 t;
#pragma unroll
        for (int j = 0; j < 8; ++j) t[j] = f2bf(p[(size_t)j * DHEAD]);
        *(u16x8*)&Vt[ln * LDK + pos0] = t;
    }
    // ---- stage S^T = L_c + lam^(c&3 chunks) * G_g  (2 coalesced tile reads) ----
    {
        const int r = tid >> 2, ccol = (tid & 3) * 16;
        float accS[16];
        if (c & 3) {
            const unsigned short* lp = Lg + ((size_t)(bh * NC + c) << 12) + (size_t)tid * 16;
            const u16x8 a0 = *(const u16x8*)lp;
            const u16x8 a1 = *(const u16x8*)(lp + 8);
#pragma unroll
            for (int j = 0; j < 8; ++j) { accS[j] = bf2f(a0[j]); accS[8 + j] = bf2f(a1[j]); }
        } else {
#pragma unroll
            for (int j = 0; j < 16; ++j) accS[j] = 0.f;
        }
        if (g) {
            const float w = exp2f(sh * (float)(CHUNK * (c - 4 * g)));
            const unsigned short* gp = Gg + ((size_t)((bh << 3) + g) << 12) + (size_t)tid * 16;
            const u16x8 t0 = *(const u16x8*)gp;
            const u16x8 t1 = *(const u16x8*)(gp + 8);
#pragma unroll
            for (int j = 0; j < 8; ++j) { accS[j] += w * bf2f(t0[j]); accS[8 + j] += w * bf2f(t1[j]); }
        }
        u16x8 w0, w1;
#pragma unroll
        for (int j = 0; j < 8; ++j) { w0[j] = f2bf(accS[j]); w1[j] = f2bf(accS[8 + j]); }
        *(u16x8*)&ShL[r * LDK + ccol]     = w0;
        *(u16x8*)&ShL[r * LDK + ccol + 8] = w1;
    }

    // ---- Q A-fragments ----
    bf16x8 aQ[2];
    {
        const float* qrow = qp + (size_t)(wv * 16 + lnlo) * DHEAD;
#pragma unroll
        for (int ks = 0; ks < 2; ++ks) {
            const float* p = qrow + ks * 32 + quad * 8;
            bf16x8 a;
#pragma unroll
            for (int j = 0; j < 8; ++j) a[j] = (short)f2bf(p[j]);
            aQ[ks] = a;
        }
    }
    float rf[4];
#pragma unroll
    for (int r = 0; r < 4; ++r) rf[r] = exp2f((float)(wv * 16 + quad * 4 + r) * sh);

    __syncthreads();

    // ---- cross: o = Q.S ----
    f32x4 o[4];
#pragma unroll
    for (int nt = 0; nt < 4; ++nt) {
        f32x4 a = (f32x4){0.f, 0.f, 0.f, 0.f};
#pragma unroll
        for (int ks = 0; ks < 2; ++ks) {
            const bf16x8 bs = *(const bf16x8*)&ShL[(nt * 16 + lnlo) * LDK + ks * 32 + quad * 8];
            a = __builtin_amdgcn_mfma_f32_16x16x32_bf16(aQ[ks], bs, a, 0, 0, 0);
        }
        o[nt] = a;
    }

    // ---- intra scores ----
    f32x4 acc[4];
#pragma unroll
    for (int nt = 0; nt < 4; ++nt) {
        f32x4 a = (f32x4){0.f, 0.f, 0.f, 0.f};
#pragma unroll
        for (int ks = 0; ks < 2; ++ks) {
            const bf16x8 bk = *(const bf16x8*)&Ks[(nt * 16 + lnlo) * LDK + ks * 32 + quad * 8];
            a = __builtin_amdgcn_mfma_f32_16x16x32_bf16(aQ[ks], bk, a, 0, 0, 0);
        }
        acc[nt] = a;
    }

    // scale cross by scale * lam^(i_local)
#pragma unroll
    for (int nt = 0; nt < 4; ++nt)
#pragma unroll
        for (int r = 0; r < 4; ++r) o[nt][r] *= rf[r] * scale;

    __syncthreads();   // all waves done reading ShL before it becomes Ws

    // ---- decay*scale*causal; C-layout -> A-layout via LDS (same-wave rows) ----
#pragma unroll
    for (int nt = 0; nt < 4; ++nt) {
        const int jn = nt * 16 + lnlo;
        const float cf = scale * exp2f(-(float)jn * sh);
#pragma unroll
        for (int r = 0; r < 4; ++r) {
            const int ri = wv * 16 + quad * 4 + r;
            float wgt = acc[nt][r] * rf[r] * cf;
            if (ri < jn) wgt = 0.0f;
            ShL[ri * LDK + jn] = f2bf(wgt);
        }
    }
    const bf16x8 aW0 = *(const bf16x8*)&ShL[(wv * 16 + lnlo) * LDK + quad * 8];
    const bf16x8 aW1 = *(const bf16x8*)&ShL[(wv * 16 + lnlo) * LDK + 32 + quad * 8];

    // ---- O += P V ----
#pragma unroll
    for (int nt = 0; nt < 4; ++nt) {
        const bf16x8 bv0 = *(const bf16x8*)&Vt[(nt * 16 + lnlo) * LDK + quad * 8];
        const bf16x8 bv1 = *(const bf16x8*)&Vt[(nt * 16 + lnlo) * LDK + 32 + quad * 8];
        o[nt] = __builtin_amdgcn_mfma_f32_16x16x32_bf16(aW0, bv0, o[nt], 0, 0, 0);
        o[nt] = __builtin_amdgcn_mfma_f32_16x16x32_bf16(aW1, bv1, o[nt], 0, 0, 0);
    }

    // ---- epilogue: bounce through LDS -> coalesced dwordx4 stores ----
    __syncthreads();   // all waves done with Ks/Vt/ShL before overlay
    float* const Of = (float*)smem;   // 64 x 68 fp32 = 17408 B (< Ks+Vt = 18432 B)
#pragma unroll
    for (int nt = 0; nt < 4; ++nt)
#pragma unroll
        for (int r = 0; r < 4; ++r)
            Of[(wv * 16 + quad * 4 + r) * 68 + nt * 16 + lnlo] = o[nt][r];
    // rows [wv*16, wv*16+16) written and read by the same wave -> no barrier
    {
        const int row = tid >> 2, col0 = (tid & 3) * 16;
        const float* src = &Of[row * 68 + col0];
        float* dst = op + (size_t)row * DHEAD + col0;
        *(f32x4*)(dst + 0)  = *(const f32x4*)(src + 0);
        *(f32x4*)(dst + 4)  = *(const f32x4*)(src + 4);
        *(f32x4*)(dst + 8)  = *(const f32x4*)(src + 8);
        *(f32x4*)(dst + 12) = *(const f32x4*)(src + 12);
    }
}

extern "C" void kernel_launch(void* const* d_in, const int* in_sizes, int n_in,
                              void* d_out, int out_size, void* d_ws, size_t ws_size,
                              hipStream_t stream) {
    (void)in_sizes; (void)n_in; (void)out_size; (void)ws_size;
    const float* q = (const float*)d_in[0];
    const float* k = (const float*)d_in[1];
    const float* v = (const float*)d_in[2];
    float* o  = (float*)d_out;
    unsigned short* Ug = (unsigned short*)d_ws;                          // 8 MB bf16 chunk summaries
    unsigned short* Lg = (unsigned short*)((char*)d_ws + ( 8u << 20));   // 8 MB bf16 local prefixes
    unsigned short* Tg = (unsigned short*)((char*)d_ws + (16u << 20));   // 2 MB bf16 group totals
    unsigned short* Gg = (unsigned short*)((char*)d_ws + (18u << 20));   // 2 MB bf16 group-start states

    dim3 blk(256, 1, 1);
    ret_pA <<<dim3(NC - 1, BH, 1), blk, 0, stream>>>(k, v, Ug);   // U_31 never consumed
    ret_pB1<<<dim3(16, BH, 1),     blk, 0, stream>>>(Ug, Lg, Tg);
    ret_pB2<<<dim3(2, BH, 1),      blk, 0, stream>>>(Tg, Gg);
    ret_p3 <<<dim3(NC, BH, 1),     blk, 0, stream>>>(q, k, v, Lg, Gg, o);
}

// Round 4
// 106.532 us; speedup vs baseline: 2.2639x; 1.0435x over previous
//
#include <hip/hip_runtime.h>

// Retention forward, chunkwise-linear, 2 stream-ordered kernels (1 boundary).
//   p12: grid (8 groups x 2 e-halves, 32 bh) = 512 blocks (2/CU). Each block:
//        full weighted-K^T staged, HALF of V^T; U-fragment MFMAs for its e-half;
//        group-local register scan -> L_c (c_loc=1..3) + T_g (g<7), bf16.
//   p3 : intra + cross; S_c = L_c + sum_{g'<g} lamC^(c-4g'-4) T_g' (<=7 terms,
//        L2-hot; measured free in r1). Verified r1 code.
// Measured design rules:
//   - grid.sync ~430us @1024 blocks (r4) — never.
//   - per-block prefix re-scan = quadratic U traffic (+45us, r5) — never.
//   - cross-block flag/spin sync: 3x regression, MfmaUtil 0.4% (r2) — never.
//   - dispatch boundary ~5-7us each (r0=3disp/63, r1=2disp/64, r3=4disp/70 kernel
//     region): minimize dispatches, but never via serial depth at 1 block/CU.
//   - timed region = ~41.5us harness reset fill (fixed) + kernels.
//   - bf16 intermediates fine: threshold 4.46, measured absmax 1.0.

#define S_LEN 2048
#define DHEAD 64
#define CHUNK 64
#define NC    32
#define BH    32
#define LDK   72

typedef float  f32x4  __attribute__((ext_vector_type(4)));
typedef short  bf16x8 __attribute__((ext_vector_type(8)));
typedef unsigned short u16x8 __attribute__((ext_vector_type(8)));
typedef unsigned short u16x4 __attribute__((ext_vector_type(4)));

static __device__ __forceinline__ unsigned short f2bf(float f) {
    unsigned int u = __float_as_uint(f);
    u += 0x7FFFu + ((u >> 16) & 1u);
    return (unsigned short)(u >> 16);
}
static __device__ __forceinline__ float bf2f(unsigned short h) {
    return __uint_as_float((unsigned int)h << 16);
}

// ---------------- p12: group KV summaries + register scan, e-half split ----------------
// blockIdx.x = g*2 + eh. Full K chunk staged (weighted K^T), half V^T.
__global__ __launch_bounds__(256)
void ret_p12(const float* __restrict__ kg, const float* __restrict__ vg,
             unsigned short* __restrict__ Lg, unsigned short* __restrict__ Tg) {
    const int bx = (int)blockIdx.x, bh = (int)blockIdx.y, h = bh & 15;
    const int g = bx >> 1, eh = bx & 1;
    const int tid = (int)threadIdx.x;
    const int wv = tid >> 6, ln = tid & 63, quad = ln >> 4, lnlo = ln & 15;
    const float sh   = log2f(1.0f - exp2f(-5.0f - (float)h));   // < 0
    const float lamC = exp2f(sh * (float)CHUNK);

    __shared__ __align__(16) unsigned short Kt[CHUNK * LDK];  // lam-weighted K^T [d][j], full
    __shared__ __align__(16) unsigned short Vt[32 * LDK];     // V^T [e_loc][j], e-half

    const size_t bb = (size_t)bh * S_LEN * DHEAD;

    // V staging assignment: 8 j-groups x 32 e
    const int vj0 = (tid >> 5) * 8;          // 0..56 step 8
    const int veL = tid & 31;                // local e
    const int ve  = eh * 32 + veL;           // global e

    // register prefetch: full K (2x8), half V (8)
    float rk[2][8], rv[8];
    {
        const size_t cb0 = bb + (size_t)(4 * g) * CHUNK * DHEAD;
#pragma unroll
        for (int i2 = 0; i2 < 2; ++i2) {
            const int pos0 = wv * 8 + i2 * 32;
            const float* pK = kg + cb0 + (size_t)pos0 * DHEAD + ln;
#pragma unroll
            for (int j = 0; j < 8; ++j) rk[i2][j] = pK[(size_t)j * DHEAD];
        }
        const float* pV = vg + cb0 + (size_t)vj0 * DHEAD + ve;
#pragma unroll
        for (int j = 0; j < 8; ++j) rv[j] = pV[(size_t)j * DHEAD];
    }

    f32x4 Sreg[2];  // e-half scan state: e_loc = nt*16+lnlo, d = wv*16+quad*4+r
#pragma unroll
    for (int nt = 0; nt < 2; ++nt) Sreg[nt] = (f32x4){0.f, 0.f, 0.f, 0.f};

    for (int i = 0; i < 4; ++i) {
        const int c = 4 * g + i;
        if (i) {  // L_c = group-local state BEFORE chunk c (c_loc==0 implied zero)
            unsigned short* lp = Lg + ((size_t)(bh * NC + c) << 12);
#pragma unroll
            for (int nt = 0; nt < 2; ++nt) {
                u16x4 w;
#pragma unroll
                for (int r = 0; r < 4; ++r) w[r] = f2bf(Sreg[nt][r]);
                *(u16x4*)&lp[(eh * 32 + nt * 16 + lnlo) * 64 + wv * 16 + quad * 4] = w;
            }
        }
        if (g == 7 && i == 3) break;  // U_31 never consumed

        // stage weighted K^T (full) + V^T (half) from regs
#pragma unroll
        for (int i2 = 0; i2 < 2; ++i2) {
            const int pos0 = wv * 8 + i2 * 32;
            u16x8 tk;
#pragma unroll
            for (int j = 0; j < 8; ++j) {
                const float w = exp2f(sh * (float)(CHUNK - pos0 - j));  // lam^(C - j_local)
                tk[j] = f2bf(rk[i2][j] * w);
            }
            *(u16x8*)&Kt[ln * LDK + pos0] = tk;
        }
        {
            u16x8 tv;
#pragma unroll
            for (int j = 0; j < 8; ++j) tv[j] = f2bf(rv[j]);
            *(u16x8*)&Vt[veL * LDK + vj0] = tv;
        }
        __syncthreads();

        // prefetch next chunk while MFMAs run (skip past last-needed)
        if (i < 3 && !(g == 7 && i == 2)) {
            const size_t cbn = bb + (size_t)(c + 1) * CHUNK * DHEAD;
#pragma unroll
            for (int i2 = 0; i2 < 2; ++i2) {
                const int pos0 = wv * 8 + i2 * 32;
                const float* pK = kg + cbn + (size_t)pos0 * DHEAD + ln;
#pragma unroll
                for (int j = 0; j < 8; ++j) rk[i2][j] = pK[(size_t)j * DHEAD];
            }
            const float* pV = vg + cbn + (size_t)vj0 * DHEAD + ve;
#pragma unroll
            for (int j = 0; j < 8; ++j) rv[j] = pV[(size_t)j * DHEAD];
        }

        bf16x8 aK[2];
#pragma unroll
        for (int ks = 0; ks < 2; ++ks)
            aK[ks] = *(const bf16x8*)&Kt[(wv * 16 + lnlo) * LDK + ks * 32 + quad * 8];
#pragma unroll
        for (int nt = 0; nt < 2; ++nt) {
            f32x4 a = (f32x4){0.f, 0.f, 0.f, 0.f};
#pragma unroll
            for (int ks = 0; ks < 2; ++ks) {
                const bf16x8 bv = *(const bf16x8*)&Vt[(nt * 16 + lnlo) * LDK + ks * 32 + quad * 8];
                a = __builtin_amdgcn_mfma_f32_16x16x32_bf16(aK[ks], bv, a, 0, 0, 0);
            }
#pragma unroll
            for (int r = 0; r < 4; ++r) Sreg[nt][r] = lamC * Sreg[nt][r] + a[r];
        }
        __syncthreads();
    }

    if (g < 7) {  // T_g = sum_{j=0..3} lamC^(3-j) U_{4g+j}  (this e-half)
        unsigned short* tp = Tg + ((size_t)((bh << 3) + g) << 12);
#pragma unroll
        for (int nt = 0; nt < 2; ++nt) {
            u16x4 w;
#pragma unroll
            for (int r = 0; r < 4; ++r) w[r] = f2bf(Sreg[nt][r]);
            *(u16x4*)&tp[(eh * 32 + nt * 16 + lnlo) * 64 + wv * 16 + quad * 4] = w;
        }
    }
}

// ---------------- p3: intra + cross (7-term S build, verified r1) ----------------
__global__ __launch_bounds__(256)
void ret_p3(const float* __restrict__ qg, const float* __restrict__ kg,
            const float* __restrict__ vg, const unsigned short* __restrict__ Lg,
            const unsigned short* __restrict__ Tg, float* __restrict__ og) {
    const int c  = (int)blockIdx.x, bh = (int)blockIdx.y, h = bh & 15;
    const int tid = (int)threadIdx.x;
    const int wv = tid >> 6, ln = tid & 63, quad = ln >> 4, lnlo = ln & 15;
    const float sh    = log2f(1.0f - exp2f(-5.0f - (float)h));
    const float scale = 0.125f;
    const int g = c >> 2;

    __shared__ __align__(16) unsigned short smem[3 * CHUNK * LDK];
    unsigned short* const Ks  = smem;                   // K [pos][d]
    unsigned short* const Vt  = smem + CHUNK * LDK;     // V^T [e][pos]
    unsigned short* const ShL = smem + 2 * CHUNK * LDK; // S^T [e][d]; reused as Ws

    const size_t cb = (size_t)bh * S_LEN * DHEAD + (size_t)c * CHUNK * DHEAD;
    const float* qp = qg + cb;
    const float* kp = kg + cb;
    const float* vp = vg + cb;
    float*       op = og + cb;

    // ---- stage K [pos][d] ----
    {
        const int kr = tid >> 2, kc0 = (tid & 3) * 16;
        const float* p = kp + (size_t)kr * DHEAD + kc0;
        const f32x4 x0 = *(const f32x4*)(p + 0);
        const f32x4 x1 = *(const f32x4*)(p + 4);
        const f32x4 x2 = *(const f32x4*)(p + 8);
        const f32x4 x3 = *(const f32x4*)(p + 12);
        u16x8 w0, w1;
        w0[0]=f2bf(x0[0]); w0[1]=f2bf(x0[1]); w0[2]=f2bf(x0[2]); w0[3]=f2bf(x0[3]);
        w0[4]=f2bf(x1[0]); w0[5]=f2bf(x1[1]); w0[6]=f2bf(x1[2]); w0[7]=f2bf(x1[3]);
        w1[0]=f2bf(x2[0]); w1[1]=f2bf(x2[1]); w1[2]=f2bf(x2[2]); w1[3]=f2bf(x2[3]);
        w1[4]=f2bf(x3[0]); w1[5]=f2bf(x3[1]); w1[6]=f2bf(x3[2]); w1[7]=f2bf(x3[3]);
        *(u16x8*)&Ks[kr * LDK + kc0]     = w0;
        *(u16x8*)&Ks[kr * LDK + kc0 + 8] = w1;
    }
    // ---- stage V^T [e][pos] ----
#pragma unroll
    for (int i = 0; i < 2; ++i) {
        const int pos0 = wv * 8 + i * 32;
        const float* p = vp + (size_t)pos0 * DHEAD + ln;
        u16x8 t;
#pragma unroll
        for (int j = 0; j < 8; ++j) t[j] = f2bf(p[(size_t)j * DHEAD]);
        *(u16x8*)&Vt[ln * LDK + pos0] = t;
    }
    // ---- stage S^T = L_c + sum_{g'<g} lamC^(c-4g'-4) T_g' ----
    {
        const int r = tid >> 2, ccol = (tid & 3) * 16;
        float accS[16];
        if (c & 3) {
            const unsigned short* lp = Lg + ((size_t)(bh * NC + c) << 12) + (size_t)tid * 16;
            const u16x8 a0 = *(const u16x8*)lp;
            const u16x8 a1 = *(const u16x8*)(lp + 8);
#pragma unroll
            for (int j = 0; j < 8; ++j) { accS[j] = bf2f(a0[j]); accS[8 + j] = bf2f(a1[j]); }
        } else {
#pragma unroll
            for (int j = 0; j < 16; ++j) accS[j] = 0.f;
        }
        for (int gp = 0; gp < g; ++gp) {   // block-uniform trip count, T tiles L2-hot
            const float w = exp2f(sh * (float)(CHUNK * (c - 4 * gp - 4)));
            const unsigned short* tp = Tg + ((size_t)((bh << 3) + gp) << 12) + (size_t)tid * 16;
            const u16x8 t0 = *(const u16x8*)tp;
            const u16x8 t1 = *(const u16x8*)(tp + 8);
#pragma unroll
            for (int j = 0; j < 8; ++j) { accS[j] += w * bf2f(t0[j]); accS[8 + j] += w * bf2f(t1[j]); }
        }
        u16x8 w0, w1;
#pragma unroll
        for (int j = 0; j < 8; ++j) { w0[j] = f2bf(accS[j]); w1[j] = f2bf(accS[8 + j]); }
        *(u16x8*)&ShL[r * LDK + ccol]     = w0;
        *(u16x8*)&ShL[r * LDK + ccol + 8] = w1;
    }

    // ---- Q A-fragments ----
    bf16x8 aQ[2];
    {
        const float* qrow = qp + (size_t)(wv * 16 + lnlo) * DHEAD;
#pragma unroll
        for (int ks = 0; ks < 2; ++ks) {
            const float* p = qrow + ks * 32 + quad * 8;
            bf16x8 a;
#pragma unroll
            for (int j = 0; j < 8; ++j) a[j] = (short)f2bf(p[j]);
            aQ[ks] = a;
        }
    }
    float rf[4];
#pragma unroll
    for (int r = 0; r < 4; ++r) rf[r] = exp2f((float)(wv * 16 + quad * 4 + r) * sh);

    __syncthreads();

    // ---- cross: o = Q.S ----
    f32x4 o[4];
#pragma unroll
    for (int nt = 0; nt < 4; ++nt) {
        f32x4 a = (f32x4){0.f, 0.f, 0.f, 0.f};
#pragma unroll
        for (int ks = 0; ks < 2; ++ks) {
            const bf16x8 bs = *(const bf16x8*)&ShL[(nt * 16 + lnlo) * LDK + ks * 32 + quad * 8];
            a = __builtin_amdgcn_mfma_f32_16x16x32_bf16(aQ[ks], bs, a, 0, 0, 0);
        }
        o[nt] = a;
    }

    // ---- intra scores ----
    f32x4 acc[4];
#pragma unroll
    for (int nt = 0; nt < 4; ++nt) {
        f32x4 a = (f32x4){0.f, 0.f, 0.f, 0.f};
#pragma unroll
        for (int ks = 0; ks < 2; ++ks) {
            const bf16x8 bk = *(const bf16x8*)&Ks[(nt * 16 + lnlo) * LDK + ks * 32 + quad * 8];
            a = __builtin_amdgcn_mfma_f32_16x16x32_bf16(aQ[ks], bk, a, 0, 0, 0);
        }
        acc[nt] = a;
    }

    // scale cross by scale * lam^(i_local)
#pragma unroll
    for (int nt = 0; nt < 4; ++nt)
#pragma unroll
        for (int r = 0; r < 4; ++r) o[nt][r] *= rf[r] * scale;

    __syncthreads();   // all waves done reading ShL before it becomes Ws

    // ---- decay*scale*causal; C-layout -> A-layout via LDS (same-wave rows) ----
#pragma unroll
    for (int nt = 0; nt < 4; ++nt) {
        const int jn = nt * 16 + lnlo;
        const float cf = scale * exp2f(-(float)jn * sh);
#pragma unroll
        for (int r = 0; r < 4; ++r) {
            const int ri = wv * 16 + quad * 4 + r;
            float wgt = acc[nt][r] * rf[r] * cf;
            if (ri < jn) wgt = 0.0f;
            ShL[ri * LDK + jn] = f2bf(wgt);
        }
    }
    const bf16x8 aW0 = *(const bf16x8*)&ShL[(wv * 16 + lnlo) * LDK + quad * 8];
    const bf16x8 aW1 = *(const bf16x8*)&ShL[(wv * 16 + lnlo) * LDK + 32 + quad * 8];

    // ---- O += P V ----
#pragma unroll
    for (int nt = 0; nt < 4; ++nt) {
        const bf16x8 bv0 = *(const bf16x8*)&Vt[(nt * 16 + lnlo) * LDK + quad * 8];
        const bf16x8 bv1 = *(const bf16x8*)&Vt[(nt * 16 + lnlo) * LDK + 32 + quad * 8];
        o[nt] = __builtin_amdgcn_mfma_f32_16x16x32_bf16(aW0, bv0, o[nt], 0, 0, 0);
        o[nt] = __builtin_amdgcn_mfma_f32_16x16x32_bf16(aW1, bv1, o[nt], 0, 0, 0);
    }

    // ---- epilogue: bounce through LDS -> coalesced dwordx4 stores ----
    __syncthreads();   // all waves done with Ks/Vt/ShL before overlay
    float* const Of = (float*)smem;   // 64 x 68 fp32 = 17408 B (< Ks+Vt = 18432 B)
#pragma unroll
    for (int nt = 0; nt < 4; ++nt)
#pragma unroll
        for (int r = 0; r < 4; ++r)
            Of[(wv * 16 + quad * 4 + r) * 68 + nt * 16 + lnlo] = o[nt][r];
    // rows [wv*16, wv*16+16) written and read by the same wave -> no barrier
    {
        const int row = tid >> 2, col0 = (tid & 3) * 16;
        const float* src = &Of[row * 68 + col0];
        float* dst = op + (size_t)row * DHEAD + col0;
        *(f32x4*)(dst + 0)  = *(const f32x4*)(src + 0);
        *(f32x4*)(dst + 4)  = *(const f32x4*)(src + 4);
        *(f32x4*)(dst + 8)  = *(const f32x4*)(src + 8);
        *(f32x4*)(dst + 12) = *(const f32x4*)(src + 12);
    }
}

extern "C" void kernel_launch(void* const* d_in, const int* in_sizes, int n_in,
                              void* d_out, int out_size, void* d_ws, size_t ws_size,
                              hipStream_t stream) {
    (void)in_sizes; (void)n_in; (void)out_size; (void)ws_size;
    const float* q = (const float*)d_in[0];
    const float* k = (const float*)d_in[1];
    const float* v = (const float*)d_in[2];
    float* o  = (float*)d_out;
    unsigned short* Lg = (unsigned short*)d_ws;                          // 8 MB bf16 local prefixes
    unsigned short* Tg = (unsigned short*)((char*)d_ws + (16u << 20));   // 2 MB bf16 group totals

    dim3 blk(256, 1, 1);
    ret_p12<<<dim3(16, BH, 1), blk, 0, stream>>>(k, v, Lg, Tg);
    ret_p3 <<<dim3(NC, BH, 1), blk, 0, stream>>>(q, k, v, Lg, Tg, o);
}